// Round 3
// baseline (2764.880 us; speedup 1.0000x reference)
//
#include <hip/hip_runtime.h>
#include <stdint.h>
#include <math.h>

// ============================================================================
// ProposalDistribution: 4x fp32 GEMM [32768,512]x[512,512]^T -> exp ->
// per-row Gaussian-NLL quadratic coefficients -> JAX-threefry rejection sampler.
//
// R2 -> R3: 512-thread blocks (2 waves/SIMD, occupancy 12->25%), TN=256 per
// phase (4 phases), LDS rows padded to 132/260 words so transpose-stores are
// 2-way (free) instead of 4-way conflicted. Math path unchanged (absmax=0.0).
// ============================================================================

#define TM 128          // rows per block
#define TN 256          // cols per phase
#define KT 16           // k per staging tile
#define KDIM 512
#define NT (KDIM / KT)  // 32 tiles
#define XPAD 132        // 128 + 4: bank-swizzle, keeps 16B alignment
#define WPAD 260        // 256 + 4
#define LOG_EPS (-13.815510557964274f)   // log(1e-6)

struct U2 { uint32_t a, b; };

__device__ __forceinline__ uint32_t rotl(uint32_t v, int d) {
  return (v << d) | (v >> (32 - d));
}

// Threefry-2x32, 20 rounds — exact JAX algorithm.
__device__ __forceinline__ U2 tf2x32(uint32_t k0, uint32_t k1, uint32_t x0, uint32_t x1) {
  const uint32_t k2 = k0 ^ k1 ^ 0x1BD11BDAu;
  x0 += k0; x1 += k1;
#define TFR(r) { x0 += x1; x1 = rotl(x1, r); x1 ^= x0; }
  TFR(13) TFR(15) TFR(26) TFR(6)
  x0 += k1; x1 += k2 + 1u;
  TFR(17) TFR(29) TFR(16) TFR(24)
  x0 += k2; x1 += k0 + 2u;
  TFR(13) TFR(15) TFR(26) TFR(6)
  x0 += k0; x1 += k1 + 3u;
  TFR(17) TFR(29) TFR(16) TFR(24)
  x0 += k1; x1 += k2 + 4u;
  TFR(13) TFR(15) TFR(26) TFR(6)
  x0 += k2; x1 += k0 + 5u;
#undef TFR
  U2 r; r.a = x0; r.b = x1; return r;
}

// JAX uniform [0,1): bitcast((bits>>9)|0x3f800000) - 1.0f
__device__ __forceinline__ float bits_to_u01(uint32_t b) {
  return __uint_as_float((b >> 9) | 0x3f800000u) - 1.0f;
}

__global__ __launch_bounds__(512, 2)
void fused_proposal_kernel(const float* __restrict__ gx, const float* __restrict__ gy,
                           const float* __restrict__ Wmux, const float* __restrict__ bmux,
                           const float* __restrict__ Wsgx, const float* __restrict__ bsgx,
                           const float* __restrict__ Wmuy, const float* __restrict__ bmuy,
                           const float* __restrict__ Wsgy, const float* __restrict__ bsgy,
                           float* __restrict__ out)
{
  __shared__ float Xs[KT][XPAD];   // k-major, 128 cols used
  __shared__ float Wms[KT][WPAD];  // k-major, 256 cols used
  __shared__ float Wss[KT][WPAD];
  __shared__ double red[TM][8];    // per-row sums: [A,I,M,Q] x {x-dist, y-dist}

  const int tid = threadIdx.x;
  const int tx = tid & 31;        // col-thread 0..31
  const int ty = tid >> 5;        // row-thread 0..15
  const int r0 = blockIdx.x * TM;
  const int lr = tid >> 2;        // staging row/col 0..127
  const int q4 = (tid & 3) << 2;  // staging k offset 0,4,8,12

  for (int i = tid; i < TM * 8; i += 512) ((double*)red)[i] = 0.0;

  for (int ph = 0; ph < 4; ++ph) {
    const int dist = ph >> 1;           // 0: x-dist, 1: y-dist
    const int c0 = (ph & 1) * TN;       // col tile base
    const float* __restrict__ Xg = dist ? gy : gx;
    const float* __restrict__ Wm = dist ? Wmuy : Wmux;
    const float* __restrict__ Wv = dist ? Wsgy : Wsgx;
    const float* __restrict__ bm = dist ? bmuy : bmux;
    const float* __restrict__ bv = dist ? bsgy : bsgx;

    float am[8][8], av[8][8];
#pragma unroll
    for (int r = 0; r < 8; ++r)
#pragma unroll
      for (int c = 0; c < 8; ++c) { am[r][c] = 0.0f; av[r][c] = 0.0f; }

    const float* xp  = Xg + (size_t)(r0 + lr) * KDIM + q4;
    const float* mp0 = Wm + (size_t)(c0 + lr) * KDIM + q4;
    const float* mp1 = Wm + (size_t)(c0 + lr + 128) * KDIM + q4;
    const float* vp0 = Wv + (size_t)(c0 + lr) * KDIM + q4;
    const float* vp1 = Wv + (size_t)(c0 + lr + 128) * KDIM + q4;

    // prefetch tile 0 into registers
    float4 xa = *(const float4*)(xp);
    float4 ma = *(const float4*)(mp0);
    float4 mb = *(const float4*)(mp1);
    float4 va = *(const float4*)(vp0);
    float4 vb = *(const float4*)(vp1);

    for (int t = 0; t < NT; ++t) {
      __syncthreads();  // previous tile's readers done
      // transpose-store staged regs to k-major LDS (padded: 2-way max = free)
#define ST4(arr, col, v) { arr[q4+0][col]=v.x; arr[q4+1][col]=v.y; arr[q4+2][col]=v.z; arr[q4+3][col]=v.w; }
      ST4(Xs,  lr, xa)
      ST4(Wms, lr, ma)  ST4(Wms, lr + 128, mb)
      ST4(Wss, lr, va)  ST4(Wss, lr + 128, vb)
#undef ST4
      __syncthreads();
      if (t + 1 < NT) {            // prefetch next tile: in flight during compute
        const int ko = (t + 1) * KT;
        xa = *(const float4*)(xp + ko);
        ma = *(const float4*)(mp0 + ko);
        mb = *(const float4*)(mp1 + ko);
        va = *(const float4*)(vp0 + ko);
        vb = *(const float4*)(vp1 + ko);
      }
#pragma unroll
      for (int kk = 0; kk < KT; ++kk) {
        const float4 x0 = *(const float4*)&Xs[kk][ty * 8];
        const float4 x1 = *(const float4*)&Xs[kk][ty * 8 + 4];
        const float4 m0 = *(const float4*)&Wms[kk][tx * 4];
        const float4 m1 = *(const float4*)&Wms[kk][tx * 4 + 128];
        const float4 v0 = *(const float4*)&Wss[kk][tx * 4];
        const float4 v1 = *(const float4*)&Wss[kk][tx * 4 + 128];
        const float xr[8] = {x0.x, x0.y, x0.z, x0.w, x1.x, x1.y, x1.z, x1.w};
        const float wm[8] = {m0.x, m0.y, m0.z, m0.w, m1.x, m1.y, m1.z, m1.w};
        const float wv[8] = {v0.x, v0.y, v0.z, v0.w, v1.x, v1.y, v1.z, v1.w};
#pragma unroll
        for (int r = 0; r < 8; ++r)
#pragma unroll
          for (int c = 0; c < 8; ++c) {
            am[r][c] = fmaf(xr[r], wm[c], am[r][c]);
            av[r][c] = fmaf(xr[r], wv[c], av[r][c]);
          }
      }
    }

    // ---- epilogue: bias, exp, per-row quadratic-coefficient partials ----
    float bmr[8], bvr[8];
#pragma unroll
    for (int c = 0; c < 4; ++c) {
      bmr[c]     = bm[c0 + tx * 4 + c];
      bmr[4 + c] = bm[c0 + 128 + tx * 4 + c];
      bvr[c]     = bv[c0 + tx * 4 + c];
      bvr[4 + c] = bv[c0 + 128 + tx * 4 + c];
    }
#pragma unroll
    for (int r = 0; r < 8; ++r) {
      float pA = 0.f, pI = 0.f, pM = 0.f, pQ = 0.f;
#pragma unroll
      for (int c = 0; c < 8; ++c) {
        const float m = am[r][c] + bmr[c];
        const float s = av[r][c] + bvr[c];
        const float v = fmaxf(expf(s), 1e-6f);     // ref's fp32 'var'
        const float lg = fmaxf(s, LOG_EPS);        // log(max(exp(s),eps))
        const float inv = __builtin_amdgcn_rcpf(v);  // 1-ulp rcp
        pA += lg;
        pI += inv;
        pM += m * inv;
        pQ += m * m * inv;
      }
      // butterfly reduce over the 32 col-threads (masks<32 stay in half-wave)
#pragma unroll
      for (int msk = 1; msk < 32; msk <<= 1) {
        pA += __shfl_xor(pA, msk);
        pI += __shfl_xor(pI, msk);
        pM += __shfl_xor(pM, msk);
        pQ += __shfl_xor(pQ, msk);
      }
      if (tx == 0) {
        double* rr = &red[ty * 8 + r][dist * 4];
        rr[0] += (double)pA; rr[1] += (double)pI;
        rr[2] += (double)pM; rr[3] += (double)pQ;
      }
    }
  }

  __syncthreads();

  // ---- fused rejection sampler: one thread per row, exact JAX threefry ----
  if (tid < TM) {
    const int grow = r0 + tid;
    const double Ax = red[tid][0], Ix = red[tid][1], Mx = red[tid][2], Qx = red[tid][3];
    const double Ay = red[tid][4], Iy = red[tid][5], My = red[tid][6], Qy = red[tid][7];

    // split(key(42), 32768)[row] = threefry((0,42),(0,row))  [partitionable]
    U2 key = tf2x32(0u, 42u, 0u, (uint32_t)grow);

    float xi = 0.0f;
    bool done = false;
    for (int it = 0; it < 100000 && !done; ++it) {
      const U2 kn = tf2x32(key.a, key.b, 0u, 0u);   // split(k,3)[0]
      const U2 k1 = tf2x32(key.a, key.b, 0u, 1u);   // split(k,3)[1]
      const U2 k2 = tf2x32(key.a, key.b, 0u, 2u);   // split(k,3)[2]
      // partitionable 32-bit random_bits = XOR of the two output words
      const U2 ru = tf2x32(k1.a, k1.b, 0u, 0u);
      const U2 rx = tf2x32(k2.a, k2.b, 0u, 0u);
      const uint32_t bu = ru.a ^ ru.b;
      const uint32_t bx = rx.a ^ rx.b;
      const float u  = bits_to_u01(bu);
      const float u2 = bits_to_u01(bx);
      xi = 2.0f * u2 - 1.0f;   // exact: 2*u2 is exact, single rounding
      const double dxi = (double)xi;
      // nll = 0.5/512 * (A + Q - 2*xi*M + xi^2*I)
      const double nx = (0.5 / 512.0) * (Ax + Qx + dxi * (dxi * Ix - 2.0 * Mx));
      const double ny = (0.5 / 512.0) * (Ay + Qy + dxi * (dxi * Iy - 2.0 * My));
      done = ((double)u >= nx * ny);
      key = kn;
    }
    out[grow] = fminf(fmaxf(xi, 1e-5f), 10.0f);
  }
}

extern "C" void kernel_launch(void* const* d_in, const int* in_sizes, int n_in,
                              void* d_out, int out_size, void* d_ws, size_t ws_size,
                              hipStream_t stream) {
  const float* x    = (const float*)d_in[0];
  const float* y    = (const float*)d_in[1];
  const float* Wmux = (const float*)d_in[2];
  const float* bmux = (const float*)d_in[3];
  const float* Wsgx = (const float*)d_in[4];
  const float* bsgx = (const float*)d_in[5];
  const float* Wmuy = (const float*)d_in[6];
  const float* bmuy = (const float*)d_in[7];
  const float* Wsgy = (const float*)d_in[8];
  const float* bsgy = (const float*)d_in[9];
  (void)in_sizes; (void)n_in; (void)d_ws; (void)ws_size; (void)out_size;

  fused_proposal_kernel<<<32768 / TM, 512, 0, stream>>>(
      x, y, Wmux, bmux, Wsgx, bsgx, Wmuy, bmuy, Wsgy, bsgy, (float*)d_out);
}

// Round 4
// 1000.648 us; speedup vs baseline: 2.7631x; 2.7631x over previous
//
#include <hip/hip_runtime.h>
#include <stdint.h>
#include <math.h>

// ============================================================================
// ProposalDistribution: 4x fp32 GEMM [32768,512]x[512,512]^T -> exp ->
// per-row Gaussian-NLL quadratic coefficients -> JAX-threefry rejection sampler.
//
// R3 -> R4: R3's 512-thread block capped VGPR at 128 and spilled the 128-reg
// accumulator tile to scratch (9.8 GB HBM traffic, 2765 us). Revert to
// 256-thread blocks; get occupancy from MORE BLOCKS instead: TM=64 -> grid=512
// = 2 independent blocks/CU (2 waves/SIMD, interleaved barriers). Accumulator
// halved to 4x8x2 = 64 VGPRs -> ~140 total, far from the 256-VGPR cliff.
// ============================================================================

#define TM 64           // rows per block
#define TN 128          // cols per phase
#define KT 16           // k per staging tile
#define KDIM 512
#define NT (KDIM / KT)  // 32 tiles
#define XPAD 68         // 64 + 4: transpose-store 2-way max (free), 16B-aligned
#define WPAD 132        // 128 + 4
#define LOG_EPS (-13.815510557964274f)   // log(1e-6)

struct U2 { uint32_t a, b; };

__device__ __forceinline__ uint32_t rotl(uint32_t v, int d) {
  return (v << d) | (v >> (32 - d));
}

// Threefry-2x32, 20 rounds — exact JAX algorithm.
__device__ __forceinline__ U2 tf2x32(uint32_t k0, uint32_t k1, uint32_t x0, uint32_t x1) {
  const uint32_t k2 = k0 ^ k1 ^ 0x1BD11BDAu;
  x0 += k0; x1 += k1;
#define TFR(r) { x0 += x1; x1 = rotl(x1, r); x1 ^= x0; }
  TFR(13) TFR(15) TFR(26) TFR(6)
  x0 += k1; x1 += k2 + 1u;
  TFR(17) TFR(29) TFR(16) TFR(24)
  x0 += k2; x1 += k0 + 2u;
  TFR(13) TFR(15) TFR(26) TFR(6)
  x0 += k0; x1 += k1 + 3u;
  TFR(17) TFR(29) TFR(16) TFR(24)
  x0 += k1; x1 += k2 + 4u;
  TFR(13) TFR(15) TFR(26) TFR(6)
  x0 += k2; x1 += k0 + 5u;
#undef TFR
  U2 r; r.a = x0; r.b = x1; return r;
}

// JAX uniform [0,1): bitcast((bits>>9)|0x3f800000) - 1.0f
__device__ __forceinline__ float bits_to_u01(uint32_t b) {
  return __uint_as_float((b >> 9) | 0x3f800000u) - 1.0f;
}

__global__ __launch_bounds__(256, 1)
void fused_proposal_kernel(const float* __restrict__ gx, const float* __restrict__ gy,
                           const float* __restrict__ Wmux, const float* __restrict__ bmux,
                           const float* __restrict__ Wsgx, const float* __restrict__ bsgx,
                           const float* __restrict__ Wmuy, const float* __restrict__ bmuy,
                           const float* __restrict__ Wsgy, const float* __restrict__ bsgy,
                           float* __restrict__ out)
{
  __shared__ float Xs[KT][XPAD];   // k-major, 64 cols used
  __shared__ float Wms[KT][WPAD];  // k-major, 128 cols used
  __shared__ float Wss[KT][WPAD];
  __shared__ double red[TM][8];    // per-row sums: [A,I,M,Q] x {x-dist, y-dist}

  const int tid = threadIdx.x;
  const int tx = tid & 15;        // col-thread 0..15 (8 cols each)
  const int ty = tid >> 4;        // row-thread 0..15 (4 rows each)
  const int r0 = blockIdx.x * TM;
  const int lr = tid >> 2;        // staging row/col 0..63
  const int q4 = (tid & 3) << 2;  // staging k offset 0,4,8,12

  for (int i = tid; i < TM * 8; i += 256) ((double*)red)[i] = 0.0;

  for (int ph = 0; ph < 8; ++ph) {
    const int dist = ph >> 2;           // 0: x-dist, 1: y-dist
    const int c0 = (ph & 3) * TN;       // col tile base
    const float* __restrict__ Xg = dist ? gy : gx;
    const float* __restrict__ Wm = dist ? Wmuy : Wmux;
    const float* __restrict__ Wv = dist ? Wsgy : Wsgx;
    const float* __restrict__ bm = dist ? bmuy : bmux;
    const float* __restrict__ bv = dist ? bsgy : bsgx;

    float am[4][8], av[4][8];
#pragma unroll
    for (int r = 0; r < 4; ++r)
#pragma unroll
      for (int c = 0; c < 8; ++c) { am[r][c] = 0.0f; av[r][c] = 0.0f; }

    const float* xp  = Xg + (size_t)(r0 + lr) * KDIM + q4;
    const float* mp0 = Wm + (size_t)(c0 + lr) * KDIM + q4;
    const float* mp1 = Wm + (size_t)(c0 + lr + 64) * KDIM + q4;
    const float* vp0 = Wv + (size_t)(c0 + lr) * KDIM + q4;
    const float* vp1 = Wv + (size_t)(c0 + lr + 64) * KDIM + q4;

    // prefetch tile 0 into registers
    float4 xa = *(const float4*)(xp);
    float4 ma = *(const float4*)(mp0);
    float4 mb = *(const float4*)(mp1);
    float4 va = *(const float4*)(vp0);
    float4 vb = *(const float4*)(vp1);

    for (int t = 0; t < NT; ++t) {
      __syncthreads();  // previous tile's readers done
      // transpose-store staged regs to k-major LDS (padded: 2-way max = free)
#define ST4(arr, col, v) { arr[q4+0][col]=v.x; arr[q4+1][col]=v.y; arr[q4+2][col]=v.z; arr[q4+3][col]=v.w; }
      ST4(Xs,  lr, xa)
      ST4(Wms, lr, ma)  ST4(Wms, lr + 64, mb)
      ST4(Wss, lr, va)  ST4(Wss, lr + 64, vb)
#undef ST4
      __syncthreads();
      if (t + 1 < NT) {            // prefetch next tile: in flight during compute
        const int ko = (t + 1) * KT;
        xa = *(const float4*)(xp + ko);
        ma = *(const float4*)(mp0 + ko);
        mb = *(const float4*)(mp1 + ko);
        va = *(const float4*)(vp0 + ko);
        vb = *(const float4*)(vp1 + ko);
      }
#pragma unroll
      for (int kk = 0; kk < KT; ++kk) {
        const float4 x0 = *(const float4*)&Xs[kk][ty * 4];
        const float4 m0 = *(const float4*)&Wms[kk][tx * 4];
        const float4 m1 = *(const float4*)&Wms[kk][tx * 4 + 64];
        const float4 v0 = *(const float4*)&Wss[kk][tx * 4];
        const float4 v1 = *(const float4*)&Wss[kk][tx * 4 + 64];
        const float xr[4] = {x0.x, x0.y, x0.z, x0.w};
        const float wm[8] = {m0.x, m0.y, m0.z, m0.w, m1.x, m1.y, m1.z, m1.w};
        const float wv[8] = {v0.x, v0.y, v0.z, v0.w, v1.x, v1.y, v1.z, v1.w};
#pragma unroll
        for (int r = 0; r < 4; ++r)
#pragma unroll
          for (int c = 0; c < 8; ++c) {
            am[r][c] = fmaf(xr[r], wm[c], am[r][c]);
            av[r][c] = fmaf(xr[r], wv[c], av[r][c]);
          }
      }
    }

    // ---- epilogue: bias, exp, per-row quadratic-coefficient partials ----
    float bmr[8], bvr[8];
#pragma unroll
    for (int c = 0; c < 4; ++c) {
      bmr[c]     = bm[c0 + tx * 4 + c];
      bmr[4 + c] = bm[c0 + 64 + tx * 4 + c];
      bvr[c]     = bv[c0 + tx * 4 + c];
      bvr[4 + c] = bv[c0 + 64 + tx * 4 + c];
    }
#pragma unroll
    for (int r = 0; r < 4; ++r) {
      float pA = 0.f, pI = 0.f, pM = 0.f, pQ = 0.f;
#pragma unroll
      for (int c = 0; c < 8; ++c) {
        const float m = am[r][c] + bmr[c];
        const float s = av[r][c] + bvr[c];
        const float v = fmaxf(expf(s), 1e-6f);     // ref's fp32 'var'
        const float lg = fmaxf(s, LOG_EPS);        // log(max(exp(s),eps))
        const float inv = __builtin_amdgcn_rcpf(v);  // 1-ulp rcp
        pA += lg;
        pI += inv;
        pM += m * inv;
        pQ += m * m * inv;
      }
      // butterfly reduce over the 16 col-threads (same ty => same rows)
#pragma unroll
      for (int msk = 1; msk < 16; msk <<= 1) {
        pA += __shfl_xor(pA, msk);
        pI += __shfl_xor(pI, msk);
        pM += __shfl_xor(pM, msk);
        pQ += __shfl_xor(pQ, msk);
      }
      if (tx == 0) {
        double* rr = &red[ty * 4 + r][dist * 4];
        rr[0] += (double)pA; rr[1] += (double)pI;
        rr[2] += (double)pM; rr[3] += (double)pQ;
      }
    }
  }

  __syncthreads();

  // ---- fused rejection sampler: one thread per row, exact JAX threefry ----
  if (tid < TM) {
    const int grow = r0 + tid;
    const double Ax = red[tid][0], Ix = red[tid][1], Mx = red[tid][2], Qx = red[tid][3];
    const double Ay = red[tid][4], Iy = red[tid][5], My = red[tid][6], Qy = red[tid][7];

    // split(key(42), 32768)[row] = threefry((0,42),(0,row))  [partitionable]
    U2 key = tf2x32(0u, 42u, 0u, (uint32_t)grow);

    float xi = 0.0f;
    bool done = false;
    for (int it = 0; it < 100000 && !done; ++it) {
      const U2 kn = tf2x32(key.a, key.b, 0u, 0u);   // split(k,3)[0]
      const U2 k1 = tf2x32(key.a, key.b, 0u, 1u);   // split(k,3)[1]
      const U2 k2 = tf2x32(key.a, key.b, 0u, 2u);   // split(k,3)[2]
      // partitionable 32-bit random_bits = XOR of the two output words
      const U2 ru = tf2x32(k1.a, k1.b, 0u, 0u);
      const U2 rx = tf2x32(k2.a, k2.b, 0u, 0u);
      const uint32_t bu = ru.a ^ ru.b;
      const uint32_t bx = rx.a ^ rx.b;
      const float u  = bits_to_u01(bu);
      const float u2 = bits_to_u01(bx);
      xi = 2.0f * u2 - 1.0f;   // exact: 2*u2 is exact, single rounding
      const double dxi = (double)xi;
      // nll = 0.5/512 * (A + Q - 2*xi*M + xi^2*I)
      const double nx = (0.5 / 512.0) * (Ax + Qx + dxi * (dxi * Ix - 2.0 * Mx));
      const double ny = (0.5 / 512.0) * (Ay + Qy + dxi * (dxi * Iy - 2.0 * My));
      done = ((double)u >= nx * ny);
      key = kn;
    }
    out[grow] = fminf(fmaxf(xi, 1e-5f), 10.0f);
  }
}

extern "C" void kernel_launch(void* const* d_in, const int* in_sizes, int n_in,
                              void* d_out, int out_size, void* d_ws, size_t ws_size,
                              hipStream_t stream) {
  const float* x    = (const float*)d_in[0];
  const float* y    = (const float*)d_in[1];
  const float* Wmux = (const float*)d_in[2];
  const float* bmux = (const float*)d_in[3];
  const float* Wsgx = (const float*)d_in[4];
  const float* bsgx = (const float*)d_in[5];
  const float* Wmuy = (const float*)d_in[6];
  const float* bmuy = (const float*)d_in[7];
  const float* Wsgy = (const float*)d_in[8];
  const float* bsgy = (const float*)d_in[9];
  (void)in_sizes; (void)n_in; (void)d_ws; (void)ws_size; (void)out_size;

  fused_proposal_kernel<<<32768 / TM, 256, 0, stream>>>(
      x, y, Wmux, bmux, Wsgx, bsgx, Wmuy, bmuy, Wsgy, bsgy, (float*)d_out);
}

// Round 5
// 791.336 us; speedup vs baseline: 3.4939x; 1.2645x over previous
//
#include <hip/hip_runtime.h>
#include <stdint.h>
#include <math.h>

// ============================================================================
// ProposalDistribution: 4x fp32 GEMM [32768,512]x[512,512]^T -> exp ->
// per-row Gaussian-NLL quadratic coefficients -> JAX-threefry rejection sampler.
//
// R4 -> R5: move the GEMM to matrix cores. fp32 is emulated by 2-way fp16
// split (a=ah+al, 3 MFMA products ah*bh + ah*bl + al*bh, fp32 accumulate):
// error ~3e-7 relative, same class as the fp32-accumulation noise the passing
// R4 kernel already had. W is pre-split once into d_ws by a tiny kernel
// (4 MB; ws_size-guarded with R4 vector kernel as fallback). Inputs pre-scaled
// x*16, W*1024 (exact pow2) so fp16 lo-parts stay normal; unscale 2^-14.
// MFMA floor: 206 GFLOP @ 2382 TF = 87 us (vs 437 us fp32-vector floor).
// ============================================================================

typedef _Float16 f16;
typedef __attribute__((ext_vector_type(8))) _Float16 f16x8;
typedef __attribute__((ext_vector_type(4))) _Float16 f16x4;
typedef __attribute__((ext_vector_type(4))) float f32x4;

#define SX 16.0f
#define SW 1024.0f
#define INV_S (1.0f / 16384.0f)
#define LOG_EPS (-13.815510557964274f)   // log(1e-6)
#define PLANE 262144                      // 512*512 elements per f16 plane
#define WS_NEED (4u * 2u * PLANE * 2u)    // 4 mats x (hi+lo) x 2B = 4 MB

struct U2 { uint32_t a, b; };

__device__ __forceinline__ uint32_t rotl(uint32_t v, int d) {
  return (v << d) | (v >> (32 - d));
}

// Threefry-2x32, 20 rounds — exact JAX algorithm.
__device__ __forceinline__ U2 tf2x32(uint32_t k0, uint32_t k1, uint32_t x0, uint32_t x1) {
  const uint32_t k2 = k0 ^ k1 ^ 0x1BD11BDAu;
  x0 += k0; x1 += k1;
#define TFR(r) { x0 += x1; x1 = rotl(x1, r); x1 ^= x0; }
  TFR(13) TFR(15) TFR(26) TFR(6)
  x0 += k1; x1 += k2 + 1u;
  TFR(17) TFR(29) TFR(16) TFR(24)
  x0 += k2; x1 += k0 + 2u;
  TFR(13) TFR(15) TFR(26) TFR(6)
  x0 += k0; x1 += k1 + 3u;
  TFR(17) TFR(29) TFR(16) TFR(24)
  x0 += k1; x1 += k2 + 4u;
  TFR(13) TFR(15) TFR(26) TFR(6)
  x0 += k2; x1 += k0 + 5u;
#undef TFR
  U2 r; r.a = x0; r.b = x1; return r;
}

__device__ __forceinline__ float bits_to_u01(uint32_t b) {
  return __uint_as_float((b >> 9) | 0x3f800000u) - 1.0f;
}

// ---------------------------------------------------------------------------
// Pre-kernel: split 4 W matrices (fp32, scaled by 1024) into fp16 hi/lo planes.
// ws layout: mat m -> hi plane at m*2*PLANE, lo plane at m*2*PLANE + PLANE.
// mats: 0=W_mu_x, 1=W_sg_x, 2=W_mu_y, 3=W_sg_y. Row-major [outcol][k].
// ---------------------------------------------------------------------------
__global__ __launch_bounds__(256) void convert_w_kernel(
    const float* __restrict__ w0, const float* __restrict__ w1,
    const float* __restrict__ w2, const float* __restrict__ w3,
    f16* __restrict__ ws)
{
  const int mat = blockIdx.x >> 8;
  const int idx = (((blockIdx.x & 255) << 8) | threadIdx.x) << 2;
  const float* W = (mat == 0) ? w0 : (mat == 1) ? w1 : (mat == 2) ? w2 : w3;
  float4 v = *(const float4*)(W + idx);
  f16* hi = ws + (size_t)mat * (2 * PLANE) + idx;
  f16* lo = hi + PLANE;
  float a[4] = {v.x, v.y, v.z, v.w};
  f16 h[4], l[4];
#pragma unroll
  for (int i = 0; i < 4; ++i) {
    float as = a[i] * SW;
    f16 hh = (f16)as;
    h[i] = hh;
    l[i] = (f16)(as - (float)hh);
  }
  *(f16x4*)hi = (f16x4){h[0], h[1], h[2], h[3]};
  *(f16x4*)lo = (f16x4){l[0], l[1], l[2], l[3]};
}

// ---------------------------------------------------------------------------
// Main MFMA kernel. 512 blocks x 256 threads (4 waves). TM=64 rows/block;
// per round (dist, colgroup of 128, kc chunk of 32): stage X split + W planes
// into LDS (register-prefetched), 48 MFMAs per wave. Epilogue folds each
// colgroup into per-row A,I,M,Q sums (double, LDS); threefry sampler at end.
// ---------------------------------------------------------------------------
__global__ __launch_bounds__(256, 2)
void mfma_proposal_kernel(const float* __restrict__ gx, const float* __restrict__ gy,
                          const float* __restrict__ bmux, const float* __restrict__ bsgx,
                          const float* __restrict__ bmuy, const float* __restrict__ bsgy,
                          const f16* __restrict__ ws, float* __restrict__ out)
{
  __shared__ f16 Xh[64][40], Xl[64][40];        // [row][k] pitch 40 (2-way max)
  __shared__ f16 Whm[128][40], Wlm[128][40];    // [outcol][k]
  __shared__ f16 Whv[128][40], Wlv[128][40];
  __shared__ double red[64][8];                 // [row][A,I,M,Q x 2 dists]

  const int tid = threadIdx.x;
  const int lane = tid & 63;
  const int w = tid >> 6;           // wave 0..3 -> rows w*16..+16
  const int ln = lane & 15;         // frag row/col
  const int quad = lane >> 4;       // frag k-quad
  const int q8 = quad * 8;
  const int r0 = blockIdx.x * 64;

  // staging indices (fixed per thread)
  const int xrow = tid >> 2, xseg = (tid & 3) * 8;   // X: 8 fp32 each
  const int wr1 = tid >> 2, wr2 = wr1 + 64, wsegk = (tid & 3) * 8;

  for (int i = tid; i < 64 * 8; i += 256) ((double*)red)[i] = 0.0;

  float4 wreg[8];   // prefetched W fp16 chunks (as raw 16B)
  float4 xreg[2];   // prefetched X fp32

#define PREFETCH(D, C, K) do {                                                  \
    const float* Xg_ = (D) ? gy : gx;                                           \
    const f16* mu_ = ws + (size_t)((D) * 2    ) * (2 * PLANE);                  \
    const f16* sg_ = ws + (size_t)((D) * 2 + 1) * (2 * PLANE);                  \
    const int k0_ = (K) * 32;                                                   \
    const float* xp_ = Xg_ + (size_t)(r0 + xrow) * 512 + k0_ + xseg;            \
    xreg[0] = *(const float4*)(xp_);                                            \
    xreg[1] = *(const float4*)(xp_ + 4);                                        \
    const size_t wo1 = (size_t)((C) * 128 + wr1) * 512 + k0_ + wsegk;           \
    const size_t wo2 = (size_t)((C) * 128 + wr2) * 512 + k0_ + wsegk;           \
    wreg[0] = *(const float4*)(mu_ + wo1);                                      \
    wreg[1] = *(const float4*)(mu_ + wo2);                                      \
    wreg[2] = *(const float4*)(mu_ + PLANE + wo1);                              \
    wreg[3] = *(const float4*)(mu_ + PLANE + wo2);                              \
    wreg[4] = *(const float4*)(sg_ + wo1);                                      \
    wreg[5] = *(const float4*)(sg_ + wo2);                                      \
    wreg[6] = *(const float4*)(sg_ + PLANE + wo1);                              \
    wreg[7] = *(const float4*)(sg_ + PLANE + wo2);                              \
  } while (0)

  PREFETCH(0, 0, 0);

  f32x4 accm[8], accv[8];

  for (int rid = 0; rid < 128; ++rid) {
    const int kc = rid & 15;
    const int cg = (rid >> 4) & 3;
    const int dist = rid >> 6;

    if (kc == 0) {
#pragma unroll
      for (int t = 0; t < 8; ++t) { accm[t] = (f32x4)0.0f; accv[t] = (f32x4)0.0f; }
    }

    __syncthreads();   // previous round's readers done

    // stage W planes (raw copy)
    *(float4*)&Whm[wr1][wsegk] = wreg[0];
    *(float4*)&Whm[wr2][wsegk] = wreg[1];
    *(float4*)&Wlm[wr1][wsegk] = wreg[2];
    *(float4*)&Wlm[wr2][wsegk] = wreg[3];
    *(float4*)&Whv[wr1][wsegk] = wreg[4];
    *(float4*)&Whv[wr2][wsegk] = wreg[5];
    *(float4*)&Wlv[wr1][wsegk] = wreg[6];
    *(float4*)&Wlv[wr2][wsegk] = wreg[7];
    // split-convert X and stage
    {
      const float xs[8] = {xreg[0].x, xreg[0].y, xreg[0].z, xreg[0].w,
                           xreg[1].x, xreg[1].y, xreg[1].z, xreg[1].w};
      f16x8 hv, lv;
#pragma unroll
      for (int i = 0; i < 8; ++i) {
        float as = xs[i] * SX;
        f16 hh = (f16)as;
        hv[i] = hh;
        lv[i] = (f16)(as - (float)hh);
      }
      *(f16x8*)&Xh[xrow][xseg] = hv;
      *(f16x8*)&Xl[xrow][xseg] = lv;
    }

    __syncthreads();

    if (rid + 1 < 128) {   // prefetch next round: VMEM in flight during MFMA
      const int n = rid + 1;
      PREFETCH(n >> 6, (n >> 4) & 3, n & 15);
    }

    // ---- 48 MFMAs: 8 col-tiles x 2 mats x 3 split-products ----
    const f16x8 ah = *(const f16x8*)&Xh[w * 16 + ln][q8];
    const f16x8 al = *(const f16x8*)&Xl[w * 16 + ln][q8];
#pragma unroll
    for (int t = 0; t < 8; ++t) {
      const int br = t * 16 + ln;
      const f16x8 bhm = *(const f16x8*)&Whm[br][q8];
      const f16x8 blm = *(const f16x8*)&Wlm[br][q8];
      const f16x8 bhv = *(const f16x8*)&Whv[br][q8];
      const f16x8 blv = *(const f16x8*)&Wlv[br][q8];
      accm[t] = __builtin_amdgcn_mfma_f32_16x16x32_f16(al, bhm, accm[t], 0, 0, 0);
      accm[t] = __builtin_amdgcn_mfma_f32_16x16x32_f16(ah, blm, accm[t], 0, 0, 0);
      accm[t] = __builtin_amdgcn_mfma_f32_16x16x32_f16(ah, bhm, accm[t], 0, 0, 0);
      accv[t] = __builtin_amdgcn_mfma_f32_16x16x32_f16(al, bhv, accv[t], 0, 0, 0);
      accv[t] = __builtin_amdgcn_mfma_f32_16x16x32_f16(ah, blv, accv[t], 0, 0, 0);
      accv[t] = __builtin_amdgcn_mfma_f32_16x16x32_f16(ah, bhv, accv[t], 0, 0, 0);
    }

    // ---- epilogue per (dist, colgroup): fold into per-row A,I,M,Q ----
    if (kc == 15) {
      const float* bmu = dist ? bmuy : bmux;
      const float* bsg = dist ? bsgy : bsgx;
      float pA[4] = {0, 0, 0, 0}, pI[4] = {0, 0, 0, 0};
      float pM[4] = {0, 0, 0, 0}, pQ[4] = {0, 0, 0, 0};
#pragma unroll
      for (int t = 0; t < 8; ++t) {
        const int col = cg * 128 + t * 16 + ln;
        const float bm_ = bmu[col], bv_ = bsg[col];
#pragma unroll
        for (int g = 0; g < 4; ++g) {
          const float m = accm[t][g] * INV_S + bm_;
          const float s = accv[t][g] * INV_S + bv_;
          const float vv = fmaxf(expf(s), 1e-6f);
          const float lg = fmaxf(s, LOG_EPS);
          const float iv = __builtin_amdgcn_rcpf(vv);
          pA[g] += lg;
          pI[g] += iv;
          pM[g] += m * iv;
          pQ[g] += m * m * iv;
        }
      }
#pragma unroll
      for (int msk = 1; msk < 16; msk <<= 1) {
#pragma unroll
        for (int g = 0; g < 4; ++g) {
          pA[g] += __shfl_xor(pA[g], msk);
          pI[g] += __shfl_xor(pI[g], msk);
          pM[g] += __shfl_xor(pM[g], msk);
          pQ[g] += __shfl_xor(pQ[g], msk);
        }
      }
      if (ln == 0) {
#pragma unroll
        for (int g = 0; g < 4; ++g) {
          double* rr = &red[w * 16 + quad * 4 + g][dist * 4];
          rr[0] += (double)pA[g]; rr[1] += (double)pI[g];
          rr[2] += (double)pM[g]; rr[3] += (double)pQ[g];
        }
      }
    }
  }

  __syncthreads();

  // ---- fused rejection sampler: one thread per row, exact JAX threefry ----
  if (tid < 64) {
    const int grow = r0 + tid;
    const double Ax = red[tid][0], Ix = red[tid][1], Mx = red[tid][2], Qx = red[tid][3];
    const double Ay = red[tid][4], Iy = red[tid][5], My = red[tid][6], Qy = red[tid][7];

    U2 key = tf2x32(0u, 42u, 0u, (uint32_t)grow);   // partitionable split

    float xi = 0.0f;
    bool done = false;
    for (int it = 0; it < 100000 && !done; ++it) {
      const U2 kn = tf2x32(key.a, key.b, 0u, 0u);
      const U2 k1 = tf2x32(key.a, key.b, 0u, 1u);
      const U2 k2 = tf2x32(key.a, key.b, 0u, 2u);
      const U2 ru = tf2x32(k1.a, k1.b, 0u, 0u);
      const U2 rx = tf2x32(k2.a, k2.b, 0u, 0u);
      const float u  = bits_to_u01(ru.a ^ ru.b);
      const float u2 = bits_to_u01(rx.a ^ rx.b);
      xi = 2.0f * u2 - 1.0f;
      const double dxi = (double)xi;
      const double nx = (0.5 / 512.0) * (Ax + Qx + dxi * (dxi * Ix - 2.0 * Mx));
      const double ny = (0.5 / 512.0) * (Ay + Qy + dxi * (dxi * Iy - 2.0 * My));
      done = ((double)u >= nx * ny);
      key = kn;
    }
    out[grow] = fminf(fmaxf(xi, 1e-5f), 10.0f);
  }
}

// ---------------------------------------------------------------------------
// Fallback: R4's passing fp32-vector kernel (used only if ws_size < 4 MB).
// ---------------------------------------------------------------------------
#define VTM 64
#define VTN 128
#define VKT 16
#define VNT 32
#define VXPAD 68
#define VWPAD 132

__global__ __launch_bounds__(256, 1)
void fused_proposal_vec(const float* __restrict__ gx, const float* __restrict__ gy,
                        const float* __restrict__ Wmux, const float* __restrict__ bmux,
                        const float* __restrict__ Wsgx, const float* __restrict__ bsgx,
                        const float* __restrict__ Wmuy, const float* __restrict__ bmuy,
                        const float* __restrict__ Wsgy, const float* __restrict__ bsgy,
                        float* __restrict__ out)
{
  __shared__ float Xs[VKT][VXPAD];
  __shared__ float Wms[VKT][VWPAD];
  __shared__ float Wss[VKT][VWPAD];
  __shared__ double red[VTM][8];

  const int tid = threadIdx.x;
  const int tx = tid & 15;
  const int ty = tid >> 4;
  const int r0 = blockIdx.x * VTM;
  const int lr = tid >> 2;
  const int q4 = (tid & 3) << 2;

  for (int i = tid; i < VTM * 8; i += 256) ((double*)red)[i] = 0.0;

  for (int ph = 0; ph < 8; ++ph) {
    const int dist = ph >> 2;
    const int c0 = (ph & 3) * VTN;
    const float* __restrict__ Xg = dist ? gy : gx;
    const float* __restrict__ Wm = dist ? Wmuy : Wmux;
    const float* __restrict__ Wv = dist ? Wsgy : Wsgx;
    const float* __restrict__ bm = dist ? bmuy : bmux;
    const float* __restrict__ bv = dist ? bsgy : bsgx;

    float am[4][8], av[4][8];
#pragma unroll
    for (int r = 0; r < 4; ++r)
#pragma unroll
      for (int c = 0; c < 8; ++c) { am[r][c] = 0.0f; av[r][c] = 0.0f; }

    const float* xp  = Xg + (size_t)(r0 + lr) * 512 + q4;
    const float* mp0 = Wm + (size_t)(c0 + lr) * 512 + q4;
    const float* mp1 = Wm + (size_t)(c0 + lr + 64) * 512 + q4;
    const float* vp0 = Wv + (size_t)(c0 + lr) * 512 + q4;
    const float* vp1 = Wv + (size_t)(c0 + lr + 64) * 512 + q4;

    float4 xa = *(const float4*)(xp);
    float4 ma = *(const float4*)(mp0);
    float4 mb = *(const float4*)(mp1);
    float4 va = *(const float4*)(vp0);
    float4 vb = *(const float4*)(vp1);

    for (int t = 0; t < VNT; ++t) {
      __syncthreads();
#define ST4(arr, col, v) { arr[q4+0][col]=v.x; arr[q4+1][col]=v.y; arr[q4+2][col]=v.z; arr[q4+3][col]=v.w; }
      ST4(Xs,  lr, xa)
      ST4(Wms, lr, ma)  ST4(Wms, lr + 64, mb)
      ST4(Wss, lr, va)  ST4(Wss, lr + 64, vb)
#undef ST4
      __syncthreads();
      if (t + 1 < VNT) {
        const int ko = (t + 1) * VKT;
        xa = *(const float4*)(xp + ko);
        ma = *(const float4*)(mp0 + ko);
        mb = *(const float4*)(mp1 + ko);
        va = *(const float4*)(vp0 + ko);
        vb = *(const float4*)(vp1 + ko);
      }
#pragma unroll
      for (int kk = 0; kk < VKT; ++kk) {
        const float4 x0 = *(const float4*)&Xs[kk][ty * 4];
        const float4 m0 = *(const float4*)&Wms[kk][tx * 4];
        const float4 m1 = *(const float4*)&Wms[kk][tx * 4 + 64];
        const float4 v0 = *(const float4*)&Wss[kk][tx * 4];
        const float4 v1 = *(const float4*)&Wss[kk][tx * 4 + 64];
        const float xr[4] = {x0.x, x0.y, x0.z, x0.w};
        const float wm[8] = {m0.x, m0.y, m0.z, m0.w, m1.x, m1.y, m1.z, m1.w};
        const float wv[8] = {v0.x, v0.y, v0.z, v0.w, v1.x, v1.y, v1.z, v1.w};
#pragma unroll
        for (int r = 0; r < 4; ++r)
#pragma unroll
          for (int c = 0; c < 8; ++c) {
            am[r][c] = fmaf(xr[r], wm[c], am[r][c]);
            av[r][c] = fmaf(xr[r], wv[c], av[r][c]);
          }
      }
    }

    float bmr[8], bvr[8];
#pragma unroll
    for (int c = 0; c < 4; ++c) {
      bmr[c]     = bm[c0 + tx * 4 + c];
      bmr[4 + c] = bm[c0 + 64 + tx * 4 + c];
      bvr[c]     = bv[c0 + tx * 4 + c];
      bvr[4 + c] = bv[c0 + 64 + tx * 4 + c];
    }
#pragma unroll
    for (int r = 0; r < 4; ++r) {
      float pA = 0.f, pI = 0.f, pM = 0.f, pQ = 0.f;
#pragma unroll
      for (int c = 0; c < 8; ++c) {
        const float m = am[r][c] + bmr[c];
        const float s = av[r][c] + bvr[c];
        const float v = fmaxf(expf(s), 1e-6f);
        const float lg = fmaxf(s, LOG_EPS);
        const float inv = __builtin_amdgcn_rcpf(v);
        pA += lg; pI += inv; pM += m * inv; pQ += m * m * inv;
      }
#pragma unroll
      for (int msk = 1; msk < 16; msk <<= 1) {
        pA += __shfl_xor(pA, msk);
        pI += __shfl_xor(pI, msk);
        pM += __shfl_xor(pM, msk);
        pQ += __shfl_xor(pQ, msk);
      }
      if (tx == 0) {
        double* rr = &red[ty * 4 + r][dist * 4];
        rr[0] += (double)pA; rr[1] += (double)pI;
        rr[2] += (double)pM; rr[3] += (double)pQ;
      }
    }
  }

  __syncthreads();

  if (tid < VTM) {
    const int grow = r0 + tid;
    const double Ax = red[tid][0], Ix = red[tid][1], Mx = red[tid][2], Qx = red[tid][3];
    const double Ay = red[tid][4], Iy = red[tid][5], My = red[tid][6], Qy = red[tid][7];
    U2 key = tf2x32(0u, 42u, 0u, (uint32_t)grow);
    float xi = 0.0f;
    bool done = false;
    for (int it = 0; it < 100000 && !done; ++it) {
      const U2 kn = tf2x32(key.a, key.b, 0u, 0u);
      const U2 k1 = tf2x32(key.a, key.b, 0u, 1u);
      const U2 k2 = tf2x32(key.a, key.b, 0u, 2u);
      const U2 ru = tf2x32(k1.a, k1.b, 0u, 0u);
      const U2 rx = tf2x32(k2.a, k2.b, 0u, 0u);
      const float u  = bits_to_u01(ru.a ^ ru.b);
      const float u2 = bits_to_u01(rx.a ^ rx.b);
      xi = 2.0f * u2 - 1.0f;
      const double dxi = (double)xi;
      const double nx = (0.5 / 512.0) * (Ax + Qx + dxi * (dxi * Ix - 2.0 * Mx));
      const double ny = (0.5 / 512.0) * (Ay + Qy + dxi * (dxi * Iy - 2.0 * My));
      done = ((double)u >= nx * ny);
      key = kn;
    }
    out[grow] = fminf(fmaxf(xi, 1e-5f), 10.0f);
  }
}

extern "C" void kernel_launch(void* const* d_in, const int* in_sizes, int n_in,
                              void* d_out, int out_size, void* d_ws, size_t ws_size,
                              hipStream_t stream) {
  const float* x    = (const float*)d_in[0];
  const float* y    = (const float*)d_in[1];
  const float* Wmux = (const float*)d_in[2];
  const float* bmux = (const float*)d_in[3];
  const float* Wsgx = (const float*)d_in[4];
  const float* bsgx = (const float*)d_in[5];
  const float* Wmuy = (const float*)d_in[6];
  const float* bmuy = (const float*)d_in[7];
  const float* Wsgy = (const float*)d_in[8];
  const float* bsgy = (const float*)d_in[9];
  (void)in_sizes; (void)n_in; (void)out_size;

  if (ws_size >= (size_t)WS_NEED) {
    convert_w_kernel<<<1024, 256, 0, stream>>>(Wmux, Wsgx, Wmuy, Wsgy, (f16*)d_ws);
    mfma_proposal_kernel<<<512, 256, 0, stream>>>(
        x, y, bmux, bsgx, bmuy, bsgy, (const f16*)d_ws, (float*)d_out);
  } else {
    fused_proposal_vec<<<512, 256, 0, stream>>>(
        x, y, Wmux, bmux, Wsgx, bsgx, Wmuy, bmuy, Wsgy, bsgy, (float*)d_out);
  }
}

// Round 6
// 395.957 us; speedup vs baseline: 6.9828x; 1.9985x over previous
//
#include <hip/hip_runtime.h>
#include <stdint.h>
#include <math.h>

// ============================================================================
// ProposalDistribution: 4x fp32 GEMM [32768,512]x[512,512]^T -> exp ->
// per-row Gaussian-NLL quadratic coefficients -> JAX-threefry rejection sampler.
//
// R5 -> R6: R5 showed 956 MB of scratch writes (private arrays spilled) and
// MfmaUtil 12%. R6 removes the register staging file entirely: W planes are
// staged by global_load_lds (DMA, width=16) into an XOR-swizzled unpadded LDS
// layout (seg ^ ((row>>1)&3)) that is conflict-free for both the DMA store
// order and the b128 fragment reads. Per-wave tile: 64 rows x 32 cols x both
// mats (r=4, c=2) -> 16 ds_read_b128 + 48 MFMA per round per wave, acc=64 f32.
// ============================================================================

typedef _Float16 f16;
typedef __attribute__((ext_vector_type(8))) _Float16 f16x8;
typedef __attribute__((ext_vector_type(4))) _Float16 f16x4;
typedef __attribute__((ext_vector_type(4))) float f32x4;

#define SX 16.0f
#define SW 1024.0f
#define INV_S (1.0f / 16384.0f)
#define LOG_EPS (-13.815510557964274f)   // log(1e-6)
#define PLANE 262144                      // 512*512 elements per f16 plane
#define WS_NEED (4u * 2u * PLANE * 2u)    // 4 mats x (hi+lo) x 2B = 4 MB

struct U2 { uint32_t a, b; };

__device__ __forceinline__ uint32_t rotl(uint32_t v, int d) {
  return (v << d) | (v >> (32 - d));
}

// Threefry-2x32, 20 rounds — exact JAX algorithm.
__device__ __forceinline__ U2 tf2x32(uint32_t k0, uint32_t k1, uint32_t x0, uint32_t x1) {
  const uint32_t k2 = k0 ^ k1 ^ 0x1BD11BDAu;
  x0 += k0; x1 += k1;
#define TFR(r) { x0 += x1; x1 = rotl(x1, r); x1 ^= x0; }
  TFR(13) TFR(15) TFR(26) TFR(6)
  x0 += k1; x1 += k2 + 1u;
  TFR(17) TFR(29) TFR(16) TFR(24)
  x0 += k2; x1 += k0 + 2u;
  TFR(13) TFR(15) TFR(26) TFR(6)
  x0 += k0; x1 += k1 + 3u;
  TFR(17) TFR(29) TFR(16) TFR(24)
  x0 += k1; x1 += k2 + 4u;
  TFR(13) TFR(15) TFR(26) TFR(6)
  x0 += k2; x1 += k0 + 5u;
#undef TFR
  U2 r; r.a = x0; r.b = x1; return r;
}

__device__ __forceinline__ float bits_to_u01(uint32_t b) {
  return __uint_as_float((b >> 9) | 0x3f800000u) - 1.0f;
}

// ---------------------------------------------------------------------------
// Pre-kernel: split 4 W matrices (fp32, scaled by 1024) into fp16 hi/lo planes.
// ws layout: mat m -> hi plane at m*2*PLANE, lo plane at +PLANE.
// mats: 0=W_mu_x, 1=W_sg_x, 2=W_mu_y, 3=W_sg_y. Row-major [outcol][k].
// ---------------------------------------------------------------------------
__global__ __launch_bounds__(256) void convert_w_kernel(
    const float* __restrict__ w0, const float* __restrict__ w1,
    const float* __restrict__ w2, const float* __restrict__ w3,
    f16* __restrict__ ws)
{
  const int mat = blockIdx.x >> 8;
  const int idx = (((blockIdx.x & 255) << 8) | threadIdx.x) << 2;
  const float* W = (mat == 0) ? w0 : (mat == 1) ? w1 : (mat == 2) ? w2 : w3;
  float4 v = *(const float4*)(W + idx);
  f16* hi = ws + (size_t)mat * (2 * PLANE) + idx;
  f16* lo = hi + PLANE;
  float a0 = v.x * SW, a1 = v.y * SW, a2 = v.z * SW, a3 = v.w * SW;
  f16 h0 = (f16)a0, h1 = (f16)a1, h2 = (f16)a2, h3 = (f16)a3;
  *(f16x4*)hi = (f16x4){h0, h1, h2, h3};
  *(f16x4*)lo = (f16x4){(f16)(a0 - (float)h0), (f16)(a1 - (float)h1),
                        (f16)(a2 - (float)h2), (f16)(a3 - (float)h3)};
}

// swizzled element offset within a [row][32] f16 LDS plane
__device__ __forceinline__ int swz_off(int row, int quad) {
  return row * 32 + ((quad ^ ((row >> 1) & 3)) << 3);
}

// ---------------------------------------------------------------------------
// Main MFMA kernel. 512 blocks x 256 threads (4 waves), 2 blocks/CU.
// Block tile: 64 rows; per round: 128 cols x 32 k, both mats, one dist.
// Rounds ordered dist(2) -> colgroup(4) -> kchunk(16) = 128 rounds.
// Wave w computes cols w*32..+32 (2 col-frags) x 64 rows (4 row-frags).
// W staged by global_load_lds (wave w stages plane w); X split in-regs.
// ---------------------------------------------------------------------------
__global__ __launch_bounds__(256, 2)
void mfma_proposal_kernel(const float* __restrict__ gx, const float* __restrict__ gy,
                          const float* __restrict__ bmux, const float* __restrict__ bsgx,
                          const float* __restrict__ bmuy, const float* __restrict__ bsgy,
                          const f16* __restrict__ ws, float* __restrict__ out)
{
  __shared__ f16 Xh[64 * 32], Xl[64 * 32];   // [row][32k] swizzled, 8 KB
  __shared__ f16 Wp[4][128 * 32];            // planes mu-hi,mu-lo,sg-hi,sg-lo, 32 KB
  __shared__ double red[4][64][8];           // per-wave slice, 16 KB

  const int tid = threadIdx.x;
  const int lane = tid & 63;
  const int w = tid >> 6;           // wave id
  const int ln = lane & 15;
  const int quad = lane >> 4;
  const int r0 = blockIdx.x * 64;

  const int xrow = tid >> 2;        // 0..63
  const int xs4 = tid & 3;          // global k-seg for X staging
  const int dma_sg = (lane & 3) ^ ((lane >> 3) & 3);  // swizzled global seg for DMA
  const int dma_row = lane >> 2;                       // row within 16-row chunk

  for (int i = tid; i < 4 * 64 * 8; i += 256) (&red[0][0][0])[i] = 0.0;

  // prefetch X tile for round 0 (dist 0, kc 0)
  const float* xbase = gx + (size_t)(r0 + xrow) * 512 + xs4 * 8;
  float4 xr0 = *(const float4*)(xbase);
  float4 xr1 = *(const float4*)(xbase + 4);

  f32x4 accm[4][2], accv[4][2];

  for (int rid = 0; rid < 128; ++rid) {
    const int kc = rid & 15;
    const int cg = (rid >> 4) & 3;
    const int dist = rid >> 6;

    if (kc == 0) {
#pragma unroll
      for (int ri = 0; ri < 4; ++ri)
#pragma unroll
        for (int cj = 0; cj < 2; ++cj) {
          accm[ri][cj] = (f32x4)0.0f;
          accv[ri][cj] = (f32x4)0.0f;
        }
    }

    __syncthreads();   // all waves done reading previous round's LDS

    // ---- W staging via global->LDS DMA: wave w stages plane w ----
    {
      // plane w: matsel = w>>1 (0 mu, 1 sg), hilo = w&1
      const f16* plane = ws + (size_t)(dist * 2 + (w >> 1)) * (2 * PLANE)
                            + (size_t)(w & 1) * PLANE;
      const int k0 = kc * 32;
      const int c0 = cg * 128;
      const f16* gp0 = plane + (size_t)(c0 + dma_row) * 512 + k0 + dma_sg * 8;
#pragma unroll
      for (int j = 0; j < 8; ++j) {
        const f16* gp = gp0 + (size_t)(j * 16) * 512;
        f16* lp = &Wp[w][(j * 16) * 32];
        __builtin_amdgcn_global_load_lds(
            (const __attribute__((address_space(1))) void*)gp,
            (__attribute__((address_space(3))) void*)lp, 16, 0, 0);
      }
    }

    // ---- X split-convert + stage (swizzled) ----
    {
      const int slot = ((xs4 ^ ((xrow >> 1) & 3)) << 3);
      float a0 = xr0.x * SX, a1 = xr0.y * SX, a2 = xr0.z * SX, a3 = xr0.w * SX;
      float a4 = xr1.x * SX, a5 = xr1.y * SX, a6 = xr1.z * SX, a7 = xr1.w * SX;
      f16 h0 = (f16)a0, h1 = (f16)a1, h2 = (f16)a2, h3 = (f16)a3;
      f16 h4 = (f16)a4, h5 = (f16)a5, h6 = (f16)a6, h7 = (f16)a7;
      *(f16x8*)&Xh[xrow * 32 + slot] = (f16x8){h0, h1, h2, h3, h4, h5, h6, h7};
      *(f16x8*)&Xl[xrow * 32 + slot] =
          (f16x8){(f16)(a0 - (float)h0), (f16)(a1 - (float)h1),
                  (f16)(a2 - (float)h2), (f16)(a3 - (float)h3),
                  (f16)(a4 - (float)h4), (f16)(a5 - (float)h5),
                  (f16)(a6 - (float)h6), (f16)(a7 - (float)h7)};
    }

    __syncthreads();   // drains DMA (vmcnt) + LDS writes before anyone reads

    // prefetch next round's X into registers (in flight during MFMAs)
    if (rid + 1 < 128) {
      const int n = rid + 1;
      const float* Xg = (n >> 6) ? gy : gx;
      const float* xp = Xg + (size_t)(r0 + xrow) * 512 + (n & 15) * 32 + xs4 * 8;
      xr0 = *(const float4*)(xp);
      xr1 = *(const float4*)(xp + 4);
    }

    // ---- compute: 48 MFMAs per wave ----
    f16x8 ah[4], al[4];
#pragma unroll
    for (int ri = 0; ri < 4; ++ri) {
      const int off = swz_off(ri * 16 + ln, quad);
      ah[ri] = *(const f16x8*)&Xh[off];
      al[ri] = *(const f16x8*)&Xl[off];
    }
#pragma unroll
    for (int cj = 0; cj < 2; ++cj) {
      const int boff = swz_off(w * 32 + cj * 16 + ln, quad);
      const f16x8 bhm = *(const f16x8*)&Wp[0][boff];
      const f16x8 blm = *(const f16x8*)&Wp[1][boff];
      const f16x8 bhv = *(const f16x8*)&Wp[2][boff];
      const f16x8 blv = *(const f16x8*)&Wp[3][boff];
#pragma unroll
      for (int ri = 0; ri < 4; ++ri) {
        accm[ri][cj] = __builtin_amdgcn_mfma_f32_16x16x32_f16(al[ri], bhm, accm[ri][cj], 0, 0, 0);
        accm[ri][cj] = __builtin_amdgcn_mfma_f32_16x16x32_f16(ah[ri], blm, accm[ri][cj], 0, 0, 0);
        accm[ri][cj] = __builtin_amdgcn_mfma_f32_16x16x32_f16(ah[ri], bhm, accm[ri][cj], 0, 0, 0);
        accv[ri][cj] = __builtin_amdgcn_mfma_f32_16x16x32_f16(al[ri], bhv, accv[ri][cj], 0, 0, 0);
        accv[ri][cj] = __builtin_amdgcn_mfma_f32_16x16x32_f16(ah[ri], blv, accv[ri][cj], 0, 0, 0);
        accv[ri][cj] = __builtin_amdgcn_mfma_f32_16x16x32_f16(ah[ri], bhv, accv[ri][cj], 0, 0, 0);
      }
    }

    // ---- epilogue per (dist, colgroup) ----
    if (kc == 15) {
      const float* bmu = dist ? bmuy : bmux;
      const float* bsg = dist ? bsgy : bsgx;
      float bm0 = bmu[cg * 128 + w * 32 + ln];
      float bm1 = bmu[cg * 128 + w * 32 + 16 + ln];
      float bv0 = bsg[cg * 128 + w * 32 + ln];
      float bv1 = bsg[cg * 128 + w * 32 + 16 + ln];
#pragma unroll
      for (int ri = 0; ri < 4; ++ri) {
#pragma unroll
        for (int g = 0; g < 4; ++g) {
          float pA = 0.f, pI = 0.f, pM = 0.f, pQ = 0.f;
#pragma unroll
          for (int cj = 0; cj < 2; ++cj) {
            const float m = accm[ri][cj][g] * INV_S + (cj ? bm1 : bm0);
            const float s = accv[ri][cj][g] * INV_S + (cj ? bv1 : bv0);
            const float vv = fmaxf(expf(s), 1e-6f);
            const float lg = fmaxf(s, LOG_EPS);
            const float iv = __builtin_amdgcn_rcpf(vv);
            pA += lg;
            pI += iv;
            pM += m * iv;
            pQ += m * m * iv;
          }
#pragma unroll
          for (int msk = 1; msk < 16; msk <<= 1) {
            pA += __shfl_xor(pA, msk);
            pI += __shfl_xor(pI, msk);
            pM += __shfl_xor(pM, msk);
            pQ += __shfl_xor(pQ, msk);
          }
          if (ln == 0) {
            double* rr = &red[w][ri * 16 + quad * 4 + g][dist * 4];
            rr[0] += (double)pA; rr[1] += (double)pI;
            rr[2] += (double)pM; rr[3] += (double)pQ;
          }
        }
      }
    }
  }

  __syncthreads();

  // ---- fused rejection sampler: one thread per row, exact JAX threefry ----
  if (tid < 64) {
    const int grow = r0 + tid;
    double Ax = 0, Ix = 0, Mx = 0, Qx = 0, Ay = 0, Iy = 0, My = 0, Qy = 0;
#pragma unroll
    for (int s = 0; s < 4; ++s) {
      Ax += red[s][tid][0]; Ix += red[s][tid][1];
      Mx += red[s][tid][2]; Qx += red[s][tid][3];
      Ay += red[s][tid][4]; Iy += red[s][tid][5];
      My += red[s][tid][6]; Qy += red[s][tid][7];
    }

    U2 key = tf2x32(0u, 42u, 0u, (uint32_t)grow);   // partitionable split

    float xi = 0.0f;
    bool done = false;
    for (int it = 0; it < 100000 && !done; ++it) {
      const U2 kn = tf2x32(key.a, key.b, 0u, 0u);
      const U2 k1 = tf2x32(key.a, key.b, 0u, 1u);
      const U2 k2 = tf2x32(key.a, key.b, 0u, 2u);
      const U2 ru = tf2x32(k1.a, k1.b, 0u, 0u);
      const U2 rx = tf2x32(k2.a, k2.b, 0u, 0u);
      const float u  = bits_to_u01(ru.a ^ ru.b);
      const float u2 = bits_to_u01(rx.a ^ rx.b);
      xi = 2.0f * u2 - 1.0f;
      const double dxi = (double)xi;
      const double nx = (0.5 / 512.0) * (Ax + Qx + dxi * (dxi * Ix - 2.0 * Mx));
      const double ny = (0.5 / 512.0) * (Ay + Qy + dxi * (dxi * Iy - 2.0 * My));
      done = ((double)u >= nx * ny);
      key = kn;
    }
    out[grow] = fminf(fmaxf(xi, 1e-5f), 10.0f);
  }
}

// ---------------------------------------------------------------------------
// Fallback: R4's passing fp32-vector kernel (used only if ws_size < 4 MB).
// ---------------------------------------------------------------------------
__global__ __launch_bounds__(256, 1)
void fused_proposal_vec(const float* __restrict__ gx, const float* __restrict__ gy,
                        const float* __restrict__ Wmux, const float* __restrict__ bmux,
                        const float* __restrict__ Wsgx, const float* __restrict__ bsgx,
                        const float* __restrict__ Wmuy, const float* __restrict__ bmuy,
                        const float* __restrict__ Wsgy, const float* __restrict__ bsgy,
                        float* __restrict__ out)
{
  __shared__ float Xs[16][68];
  __shared__ float Wms[16][132];
  __shared__ float Wss[16][132];
  __shared__ double red[64][8];

  const int tid = threadIdx.x;
  const int tx = tid & 15;
  const int ty = tid >> 4;
  const int r0 = blockIdx.x * 64;
  const int lr = tid >> 2;
  const int q4 = (tid & 3) << 2;

  for (int i = tid; i < 64 * 8; i += 256) ((double*)red)[i] = 0.0;

  for (int ph = 0; ph < 8; ++ph) {
    const int dist = ph >> 2;
    const int c0 = (ph & 3) * 128;
    const float* __restrict__ Xg = dist ? gy : gx;
    const float* __restrict__ Wm = dist ? Wmuy : Wmux;
    const float* __restrict__ Wv = dist ? Wsgy : Wsgx;
    const float* __restrict__ bm = dist ? bmuy : bmux;
    const float* __restrict__ bv = dist ? bsgy : bsgx;

    float am[4][8], av[4][8];
#pragma unroll
    for (int r = 0; r < 4; ++r)
#pragma unroll
      for (int c = 0; c < 8; ++c) { am[r][c] = 0.0f; av[r][c] = 0.0f; }

    const float* xp  = Xg + (size_t)(r0 + lr) * 512 + q4;
    const float* mp0 = Wm + (size_t)(c0 + lr) * 512 + q4;
    const float* mp1 = Wm + (size_t)(c0 + lr + 64) * 512 + q4;
    const float* vp0 = Wv + (size_t)(c0 + lr) * 512 + q4;
    const float* vp1 = Wv + (size_t)(c0 + lr + 64) * 512 + q4;

    float4 xa = *(const float4*)(xp);
    float4 ma = *(const float4*)(mp0);
    float4 mb = *(const float4*)(mp1);
    float4 va = *(const float4*)(vp0);
    float4 vb = *(const float4*)(vp1);

    for (int t = 0; t < 32; ++t) {
      __syncthreads();
#define ST4(arr, col, v) { arr[q4+0][col]=v.x; arr[q4+1][col]=v.y; arr[q4+2][col]=v.z; arr[q4+3][col]=v.w; }
      ST4(Xs,  lr, xa)
      ST4(Wms, lr, ma)  ST4(Wms, lr + 64, mb)
      ST4(Wss, lr, va)  ST4(Wss, lr + 64, vb)
#undef ST4
      __syncthreads();
      if (t + 1 < 32) {
        const int ko = (t + 1) * 16;
        xa = *(const float4*)(xp + ko);
        ma = *(const float4*)(mp0 + ko);
        mb = *(const float4*)(mp1 + ko);
        va = *(const float4*)(vp0 + ko);
        vb = *(const float4*)(vp1 + ko);
      }
#pragma unroll
      for (int kk = 0; kk < 16; ++kk) {
        const float4 x0 = *(const float4*)&Xs[kk][ty * 4];
        const float4 m0 = *(const float4*)&Wms[kk][tx * 4];
        const float4 m1 = *(const float4*)&Wms[kk][tx * 4 + 64];
        const float4 v0 = *(const float4*)&Wss[kk][tx * 4];
        const float4 v1 = *(const float4*)&Wss[kk][tx * 4 + 64];
        const float xr[4] = {x0.x, x0.y, x0.z, x0.w};
        const float wm[8] = {m0.x, m0.y, m0.z, m0.w, m1.x, m1.y, m1.z, m1.w};
        const float wv[8] = {v0.x, v0.y, v0.z, v0.w, v1.x, v1.y, v1.z, v1.w};
#pragma unroll
        for (int r = 0; r < 4; ++r)
#pragma unroll
          for (int c = 0; c < 8; ++c) {
            am[r][c] = fmaf(xr[r], wm[c], am[r][c]);
            av[r][c] = fmaf(xr[r], wv[c], av[r][c]);
          }
      }
    }

    float bmr[8], bvr[8];
#pragma unroll
    for (int c = 0; c < 4; ++c) {
      bmr[c]     = bm[c0 + tx * 4 + c];
      bmr[4 + c] = bm[c0 + 64 + tx * 4 + c];
      bvr[c]     = bv[c0 + tx * 4 + c];
      bvr[4 + c] = bv[c0 + 64 + tx * 4 + c];
    }
#pragma unroll
    for (int r = 0; r < 4; ++r) {
      float pA = 0.f, pI = 0.f, pM = 0.f, pQ = 0.f;
#pragma unroll
      for (int c = 0; c < 8; ++c) {
        const float m = am[r][c] + bmr[c];
        const float s = av[r][c] + bvr[c];
        const float v = fmaxf(expf(s), 1e-6f);
        const float lg = fmaxf(s, LOG_EPS);
        const float inv = __builtin_amdgcn_rcpf(v);
        pA += lg; pI += inv; pM += m * inv; pQ += m * m * inv;
      }
#pragma unroll
      for (int msk = 1; msk < 16; msk <<= 1) {
        pA += __shfl_xor(pA, msk);
        pI += __shfl_xor(pI, msk);
        pM += __shfl_xor(pM, msk);
        pQ += __shfl_xor(pQ, msk);
      }
      if (tx == 0) {
        double* rr = &red[ty * 4 + r][dist * 4];
        rr[0] += (double)pA; rr[1] += (double)pI;
        rr[2] += (double)pM; rr[3] += (double)pQ;
      }
    }
  }

  __syncthreads();

  if (tid < 64) {
    const int grow = r0 + tid;
    const double Ax = red[tid][0], Ix = red[tid][1], Mx = red[tid][2], Qx = red[tid][3];
    const double Ay = red[tid][4], Iy = red[tid][5], My = red[tid][6], Qy = red[tid][7];
    U2 key = tf2x32(0u, 42u, 0u, (uint32_t)grow);
    float xi = 0.0f;
    bool done = false;
    for (int it = 0; it < 100000 && !done; ++it) {
      const U2 kn = tf2x32(key.a, key.b, 0u, 0u);
      const U2 k1 = tf2x32(key.a, key.b, 0u, 1u);
      const U2 k2 = tf2x32(key.a, key.b, 0u, 2u);
      const U2 ru = tf2x32(k1.a, k1.b, 0u, 0u);
      const U2 rx = tf2x32(k2.a, k2.b, 0u, 0u);
      const float u  = bits_to_u01(ru.a ^ ru.b);
      const float u2 = bits_to_u01(rx.a ^ rx.b);
      xi = 2.0f * u2 - 1.0f;
      const double dxi = (double)xi;
      const double nx = (0.5 / 512.0) * (Ax + Qx + dxi * (dxi * Ix - 2.0 * Mx));
      const double ny = (0.5 / 512.0) * (Ay + Qy + dxi * (dxi * Iy - 2.0 * My));
      done = ((double)u >= nx * ny);
      key = kn;
    }
    out[grow] = fminf(fmaxf(xi, 1e-5f), 10.0f);
  }
}

extern "C" void kernel_launch(void* const* d_in, const int* in_sizes, int n_in,
                              void* d_out, int out_size, void* d_ws, size_t ws_size,
                              hipStream_t stream) {
  const float* x    = (const float*)d_in[0];
  const float* y    = (const float*)d_in[1];
  const float* Wmux = (const float*)d_in[2];
  const float* bmux = (const float*)d_in[3];
  const float* Wsgx = (const float*)d_in[4];
  const float* bsgx = (const float*)d_in[5];
  const float* Wmuy = (const float*)d_in[6];
  const float* bmuy = (const float*)d_in[7];
  const float* Wsgy = (const float*)d_in[8];
  const float* bsgy = (const float*)d_in[9];
  (void)in_sizes; (void)n_in; (void)out_size;

  if (ws_size >= (size_t)WS_NEED) {
    convert_w_kernel<<<1024, 256, 0, stream>>>(Wmux, Wsgx, Wmuy, Wsgy, (f16*)d_ws);
    mfma_proposal_kernel<<<512, 256, 0, stream>>>(
        x, y, bmux, bsgx, bmuy, bsgy, (const f16*)d_ws, (float*)d_out);
  } else {
    fused_proposal_vec<<<512, 256, 0, stream>>>(
        x, y, Wmux, bmux, Wsgx, bsgx, Wmuy, bmuy, Wsgy, bsgy, (float*)d_out);
  }
}